// Round 17
// baseline (203.453 us; speedup 1.0000x reference)
//
#include <hip/hip_runtime.h>
#include <math.h>

#define BN_EPS 1e-3f

typedef __attribute__((ext_vector_type(8))) unsigned short ushort8v;
typedef __attribute__((ext_vector_type(8))) short short8v;
typedef __attribute__((ext_vector_type(4))) float f32x4;
typedef __attribute__((ext_vector_type(4))) unsigned int uint4v;

__device__ __forceinline__ float4 f4load(const float* p) {
    return *reinterpret_cast<const float4*>(p);
}
__device__ __forceinline__ float bf2f(unsigned short u) {
    union { unsigned int i; float f; } w; w.i = ((unsigned int)u) << 16; return w.f;
}
__device__ __forceinline__ unsigned short f2bf(float f) {
    union { float fv; unsigned int i; } w; w.fv = f;
    unsigned int lsb = (w.i >> 16) & 1u;
    w.i += 0x7fffu + lsb;             // round-to-nearest-even
    return (unsigned short)(w.i >> 16);
}
// HW packed convert: returns [bf16(hi)<<16 | bf16(lo)] (RTNE)
__device__ __forceinline__ unsigned cvtpk(float lo, float hi) {
    unsigned r;
    asm("v_cvt_pk_bf16_f32 %0, %1, %2" : "=v"(r) : "v"(lo), "v"(hi));
    return r;
}
template<int N> __device__ __forceinline__ void waitv() {
    asm volatile("s_waitcnt vmcnt(%0)" :: "n"(N) : "memory");
}

#define GLOAD_LDS16(g, l)                                                     \
    __builtin_amdgcn_global_load_lds(                                         \
        (const __attribute__((address_space(1))) void*)(const void*)(g),      \
        (__attribute__((address_space(3))) void*)(void*)(l), 16, 0, 0)

// ---------------- Weight prep: k[tap][cin][cout] f32 ->
// frag-order Wt[it][nsg][lane][8] bf16; block 567 builds conv0 B-table
// (K=64 kd-plane-per-sg layout) + zero page.
template<int CIN, int COUT>
__device__ __forceinline__ void wprep_body(
    const float* __restrict__ k, unsigned short* __restrict__ wt, int blk)
{
    constexpr int NS = COUT / 16;
    constexpr int KS = CIN / 32;
    int idx = blk * 256 + (int)threadIdx.x;
    if (idx >= 27 * KS * NS * 64) return;
    int lane = idx & 63;
    int nsg  = (idx >> 6) % NS;
    int it   = idx / (64 * NS);
    int tap  = it / KS;
    int ks   = it - tap * KS;
    int sg = lane >> 4, lr = lane & 15;
    int cout = nsg * 16 + lr;
    ushort8v o;
    #pragma unroll
    for (int j = 0; j < 8; ++j) {
        int ci = ks * 32 + sg * 8 + j;
        o[j] = f2bf(k[(size_t)(tap * CIN + ci) * COUT + cout]);
    }
    *reinterpret_cast<ushort8v*>(wt + (size_t)idx * 8) = o;
}

__global__ __launch_bounds__(256) void wprep_all(
    const float* __restrict__ k0,
    const float* __restrict__ k1, const float* __restrict__ k2, const float* __restrict__ k3,
    unsigned short* __restrict__ w0f,
    unsigned short* __restrict__ w1, unsigned short* __restrict__ w2, unsigned short* __restrict__ w3,
    unsigned short* __restrict__ zp)
{
    int b = blockIdx.x;
    if (b < 27)       wprep_body<32, 64>(k1, w1, b);
    else if (b < 135) wprep_body<64, 128>(k2, w2, b - 27);
    else if (b < 567) wprep_body<128, 256>(k3, w3, b - 135);
    else {
        reinterpret_cast<unsigned int*>(zp)[threadIdx.x] = 0u;   // 1KB zero page
        {
            int t = (int)threadIdx.x;
            int lane = t & 63;
            int mf = (t >> 6) & 1;
            int ns = t >> 7;
            int sg = lane >> 4, lr = lane & 15;
            ushort8v o;
            #pragma unroll
            for (int j = 0; j < 8; ++j) {
                int jj = mf * 8 + j;
                bool valid = (sg < 3) && (jj < 9);
                int tap = sg * 9 + jj;
                o[j] = valid ? f2bf(k0[tap * 32 + ns * 16 + lr]) : (unsigned short)0;
            }
            *reinterpret_cast<ushort8v*>(w0f + (size_t)t * 8) = o;
        }
    }
}

// ---------------- Block 0: LDS-tiled im2col MFMA, kd-plane-per-sg K layout.
// Swapped operands (D = W·X): each lane holds 4 consecutive couts -> 8B stores.
__global__ __launch_bounds__(256) void conv0_lds(
    const float* __restrict__ x, const unsigned short* __restrict__ w0f,
    const float* __restrict__ zf,
    const float* __restrict__ b, const float* __restrict__ g,
    const float* __restrict__ be, const float* __restrict__ m,
    const float* __restrict__ v, unsigned short* __restrict__ y)
{
    __shared__ __attribute__((aligned(16))) float tile[81 * 36];  // 11664 B

    const int l   = threadIdx.x & 63;
    const int wid = threadIdx.x >> 6;
    const int sg  = l >> 4;
    const int lr  = l & 15;

    int bb = blockIdx.x;
    const int owt = bb % 3;  bb /= 3;
    const int oht = bb % 12; bb /= 12;
    const int odt = bb % 12; const int n = bb / 12;

    const int id0 = odt * 8, ih0 = oht * 8, iw0 = owt * 32;

    // ---- stage: 81 rows x 9 chunks of 16B = 729 chunks
    #pragma unroll
    for (int q0 = 0; q0 < 729; q0 += 256) {
        int qq = q0 + wid * 64;            // wave-uniform LDS chunk base
        int q  = qq + l;
        if (qq < 729 && q < 729) {
            int row = q / 9, c = q - row * 9;
            int dd = row / 9, hh = row - dd * 9;
            int id = id0 + dd, ih = ih0 + hh;
            const float* src =
                (id < 96 && ih < 96 && (c < 8 || iw0 + 32 < 96))
                ? x + ((size_t)(n * 96 + id) * 96 + ih) * 96 + iw0 + c * 4
                : zf;
            GLOAD_LDS16(src, (char*)tile + (size_t)qq * 16);
        }
    }
    __syncthreads();

    const short8v B00 = *(const short8v*)(w0f + (size_t)(0 * 64 + l) * 8);
    const short8v B01 = *(const short8v*)(w0f + (size_t)(1 * 64 + l) * 8);
    const short8v B10 = *(const short8v*)(w0f + (size_t)(2 * 64 + l) * 8);
    const short8v B11 = *(const short8v*)(w0f + (size_t)(3 * 64 + l) * 8);

    // ---- per-lane gather: 9 rows of kd-plane (sg), cols 2lr..2lr+2
    float rc[9][3];
    {
        int dcl = (sg < 3) ? (2 * wid + sg) : 0;   // sg==3: harmless (W=0)
        const float* rb = tile + (size_t)(dcl * 9) * 36 + 2 * lr;
        #pragma unroll
        for (int r = 0; r < 9; ++r) {
            float2 lo = *reinterpret_cast<const float2*>(rb + r * 36);
            rc[r][0] = lo.x; rc[r][1] = lo.y;
            rc[r][2] = rb[r * 36 + 2];
        }
    }

    f32x4 acc[4][2];
    #pragma unroll
    for (int mi = 0; mi < 4; ++mi) {
        acc[mi][0] = (f32x4){0.f, 0.f, 0.f, 0.f};
        acc[mi][1] = (f32x4){0.f, 0.f, 0.f, 0.f};
    }

    #pragma unroll
    for (int mi = 0; mi < 4; ++mi) {
        const int h0 = 2 * mi;
        uint4v au0;
        au0[0] = cvtpk(rc[h0][0],     rc[h0][1]);
        au0[1] = cvtpk(rc[h0][2],     rc[h0 + 1][0]);
        au0[2] = cvtpk(rc[h0 + 1][1], rc[h0 + 1][2]);
        au0[3] = cvtpk(rc[h0 + 2][0], rc[h0 + 2][1]);
        short8v a0 = __builtin_bit_cast(short8v, au0);
        uint4v au1;
        au1[0] = cvtpk(rc[h0 + 2][2], 0.f);
        au1[1] = 0; au1[2] = 0; au1[3] = 0;
        short8v a1 = __builtin_bit_cast(short8v, au1);
        acc[mi][0] = __builtin_amdgcn_mfma_f32_16x16x32_bf16(B00, a0, acc[mi][0], 0, 0, 0);
        acc[mi][0] = __builtin_amdgcn_mfma_f32_16x16x32_bf16(B01, a1, acc[mi][0], 0, 0, 0);
        acc[mi][1] = __builtin_amdgcn_mfma_f32_16x16x32_bf16(B10, a0, acc[mi][1], 0, 0, 0);
        acc[mi][1] = __builtin_amdgcn_mfma_f32_16x16x32_bf16(B11, a1, acc[mi][1], 0, 0, 0);
    }

    float4 Sv[2], Tv[2];
    #pragma unroll
    for (int ns = 0; ns < 2; ++ns) {
        int c0 = ns * 16 + sg * 4;
        float4 gv = f4load(g + c0), vv = f4load(v + c0);
        float4 bv = f4load(b + c0), mv = f4load(m + c0), bev = f4load(be + c0);
        Sv[ns].x = gv.x * rsqrtf(vv.x + BN_EPS);
        Sv[ns].y = gv.y * rsqrtf(vv.y + BN_EPS);
        Sv[ns].z = gv.z * rsqrtf(vv.z + BN_EPS);
        Sv[ns].w = gv.w * rsqrtf(vv.w + BN_EPS);
        Tv[ns].x = (bv.x - mv.x) * Sv[ns].x + bev.x;
        Tv[ns].y = (bv.y - mv.y) * Sv[ns].y + bev.y;
        Tv[ns].z = (bv.z - mv.z) * Sv[ns].z + bev.z;
        Tv[ns].w = (bv.w - mv.w) * Sv[ns].w + bev.w;
    }
    const int odG = odt * 4 + wid;
    const int owG = owt * 16 + lr;
    #pragma unroll
    for (int mi = 0; mi < 4; ++mi) {
        int oh = oht * 4 + mi;
        unsigned short* yp =
            y + (((size_t)(n * 48 + odG) * 48 + oh) * 48 + owG) * 32;
        #pragma unroll
        for (int ns = 0; ns < 2; ++ns) {
            float v0 = fmaxf(acc[mi][ns][0] * Sv[ns].x + Tv[ns].x, 0.f);
            float v1 = fmaxf(acc[mi][ns][1] * Sv[ns].y + Tv[ns].y, 0.f);
            float v2 = fmaxf(acc[mi][ns][2] * Sv[ns].z + Tv[ns].z, 0.f);
            float v3 = fmaxf(acc[mi][ns][3] * Sv[ns].w + Tv[ns].w, 0.f);
            uint2 uu;
            uu.x = cvtpk(v0, v1);
            uu.y = cvtpk(v2, v3);
            *reinterpret_cast<uint2*>(yp + ns * 16 + sg * 4) = uu;
        }
    }
}

// ---------------- MFMA implicit-GEMM conv, R17:
//  - A: LDS depth-3 pipeline (4 buffers), coalesced swizzled staging.
//  - B: L2-resident weights load global->VGPR directly, ping-pong one
//    iteration ahead (no LDS round-trip; Common-mistake #7).
//  - counted vmcnt with order-robust thresholds; final iter drains.
template<int CIN, int COUT, int INS, int OUTS, int MW, int NSW, int NH,
         int CSPLIT, int KU>
__global__ __launch_bounds__(256, 2) void conv_mfma_bg(
    const unsigned short* __restrict__ x, const unsigned short* __restrict__ wt,
    const unsigned short* __restrict__ zp,
    const float* __restrict__ b, const float* __restrict__ g,
    const float* __restrict__ be, const float* __restrict__ m,
    const float* __restrict__ v, unsigned short* __restrict__ y)
{
    constexpr int NSfull = COUT / 16;
    constexpr int NSB = NSW * NH;
    constexpr int KS = CIN / 32;
    constexpr int NITK = 27 * KS;
    constexpr int NIT = NITK / KU;
    constexpr int MGROUPS = 4 / NH;
    constexpr int MTILE = MGROUPS * MW * 16;
    constexpr int ASTEP = MGROUPS * MW * KU * 1024;
    constexpr int AL = MW * KU;          // A gload_lds per staging thread/iter
    constexpr int BF = NSW * KU;         // B reg-frags per thread/iter
    static_assert(NSB * CSPLIT == NSfull && NITK % KU == 0, "tiling");
    static_assert(NIT >= 5, "pipeline depth");

    __shared__ __attribute__((aligned(16))) char lds[4 * ASTEP];

    const int l   = threadIdx.x & 63;
    const int wid = threadIdx.x >> 6;
    const int sg  = l >> 4;
    const int lr  = l & 15;

    const int mblk   = blockIdx.x / CSPLIT;
    const int cchunk = blockIdx.x % CSPLIT;
    const int mgroup = wid / NH;
    const int ngroup = wid % NH;
    const bool stager = (ngroup == 0);
    const int gCoutBase = (cchunk * NSB + ngroup * NSW) * 16;
    const int vwave = mblk * MTILE + mgroup * MW * 16;

    // Staging-side lane map: lane l fetches voxel (l>>2), cin-slice
    // ((l&3) - (l>>3)) & 3  (coalesced 64B per lane-quad).
    const int vvS = l >> 2;
    const int ssS = ((l & 3) - (l >> 3)) & 3;

    const unsigned short* ap0[MW];
    unsigned smask[MW];
    #pragma unroll
    for (int mi = 0; mi < MW; ++mi) {
        int vA = vwave + mi * 16 + vvS;
        int owA = vA % OUTS; int t1 = vA / OUTS;
        int ohA = t1 % OUTS; int t2 = t1 / OUTS;
        int odA = t2 % OUTS; int nA = t2 / OUTS;
        ap0[mi] = x + ((((size_t)nA * INS + 2 * odA) * INS + 2 * ohA) * INS + 2 * owA) * CIN + ssS * 8;
        smask[mi] = ((odA == OUTS - 1) ? 0x07FC0000u : 0u)
                  | ((ohA == OUTS - 1) ? 0x070381C0u : 0u)
                  | ((owA == OUTS - 1) ? 0x04924924u : 0u);
    }

    const unsigned short* zpl = (const unsigned short*)((const char*)zp + l * 16);
    // Read-side inverse slot: lane (sg,lr) -> slot lr*4 + ((sg+(lr>>1))&3)
    const int slotA = (lr * 4 + ((sg + (lr >> 1)) & 3)) * 16;

    f32x4 acc[MW][NSW];
    #pragma unroll
    for (int mi = 0; mi < MW; ++mi)
        #pragma unroll
        for (int ns = 0; ns < NSW; ++ns) acc[mi][ns] = (f32x4){0.f, 0.f, 0.f, 0.f};

    auto astage = [&](int ito, int p) {
        if (!stager) return;
        char* dst = &lds[p * ASTEP];
        #pragma unroll
        for (int u = 0; u < KU; ++u) {
            int it = ito * KU + u;
            int tap = (KS == 1) ? it : it / KS;
            int ks  = (KS == 1) ? 0  : it - tap * KS;
            int kd = tap / 9, r9 = tap - kd * 9, kh = r9 / 3, kw = r9 - kh * 3;
            size_t aoff = (size_t)((kd * INS + kh) * INS + kw) * CIN + ks * 32;
            #pragma unroll
            for (int mi = 0; mi < MW; ++mi) {
                const unsigned short* ga =
                    ((smask[mi] >> tap) & 1u) ? zpl : (ap0[mi] + aoff);
                GLOAD_LDS16(ga, dst + ((mgroup * MW + mi) * KU + u) * 1024);
            }
        }
    };

    auto bload = [&](int ito, short8v (&B)[BF]) {
        #pragma unroll
        for (int u = 0; u < KU; ++u)
            #pragma unroll
            for (int ns = 0; ns < NSW; ++ns) {
                int it = ito * KU + u;
                B[u * NSW + ns] = *(const short8v*)(
                    wt + ((size_t)(it * NSfull + cchunk * NSB + ngroup * NSW + ns) * 64 + l) * 8);
            }
    };

    auto computestep = [&](int ito, short8v (&B)[BF]) {
        const char* buf = &lds[(ito & 3) * ASTEP];
        #pragma unroll
        for (int u = 0; u < KU; ++u) {
            short8v Af[MW];
            #pragma unroll
            for (int mi = 0; mi < MW; ++mi)
                Af[mi] = *(const short8v*)(buf + ((mgroup * MW + mi) * KU + u) * 1024 + slotA);
            #pragma unroll
            for (int mi = 0; mi < MW; ++mi)
                #pragma unroll
                for (int ns = 0; ns < NSW; ++ns)
                    acc[mi][ns] = __builtin_amdgcn_mfma_f32_16x16x32_bf16(B[u * NSW + ns], Af[mi], acc[mi][ns], 0, 0, 0);
        }
    };

    short8v Bc[BF], Bn[BF];

    // prologue: B(0) first, then A(0..2)
    bload(0, Bc);
    astage(0, 0);
    astage(1, 1);
    astage(2, 2);

    // iter 0 (even, uses Bc)
    if (stager) waitv<2 * AL>();
    __builtin_amdgcn_s_barrier();
    asm volatile("" ::: "memory");
    astage(3, 3);
    bload(1, Bn);
    computestep(0, Bc);

    // iter 1 (odd, uses Bn)
    if (stager) waitv<2 * AL + BF>();
    __builtin_amdgcn_s_barrier();
    asm volatile("" ::: "memory");
    if (4 < NIT) astage(4, 0);
    bload(2, Bc);
    computestep(1, Bn);

    // main pairs: it in [2, NIT-1)
    int it = 2;
    #pragma unroll 1
    for (; it + 1 < NIT - 1; it += 2) {
        // even half: uses Bc
        if (stager) waitv<2 * AL + 2 * BF>();
        __builtin_amdgcn_s_barrier();
        asm volatile("" ::: "memory");
        if (it + 3 < NIT) astage(it + 3, (it + 3) & 3);
        bload(it + 1, Bn);
        computestep(it, Bc);
        // odd half: uses Bn
        if (stager) waitv<2 * AL + 2 * BF>();
        __builtin_amdgcn_s_barrier();
        asm volatile("" ::: "memory");
        if (it + 4 < NIT) astage(it + 4, (it + 4) & 3);
        bload(it + 2, Bc);
        computestep(it + 1, Bn);
    }
    if (it < NIT - 1) {   // one leftover even iter before the final (NIT even)
        if (stager) waitv<2 * AL + 2 * BF>();
        __builtin_amdgcn_s_barrier();
        asm volatile("" ::: "memory");
        bload(it + 1, Bn);
        computestep(it, Bc);
        ++it;
    }
    // final iteration: full drain (once per block)
    waitv<0>();
    __builtin_amdgcn_s_barrier();
    asm volatile("" ::: "memory");
    if constexpr (((NIT - 1) & 1) == 0) computestep(NIT - 1, Bc);
    else                                computestep(NIT - 1, Bn);

    // epilogue: lane holds couts gCoutBase+ns*16+sg*4..+3 for voxel
    // vwave+mi*16+lr -> one 8B store per (mi,ns).
    float4 Sv[NSW], Tv[NSW];
    #pragma unroll
    for (int ns = 0; ns < NSW; ++ns) {
        int c0 = gCoutBase + ns * 16 + sg * 4;
        float4 gv = f4load(g + c0), vv = f4load(v + c0);
        float4 bv = f4load(b + c0), mv = f4load(m + c0), bev = f4load(be + c0);
        Sv[ns].x = gv.x * rsqrtf(vv.x + BN_EPS);
        Sv[ns].y = gv.y * rsqrtf(vv.y + BN_EPS);
        Sv[ns].z = gv.z * rsqrtf(vv.z + BN_EPS);
        Sv[ns].w = gv.w * rsqrtf(vv.w + BN_EPS);
        Tv[ns].x = (bv.x - mv.x) * Sv[ns].x + bev.x;
        Tv[ns].y = (bv.y - mv.y) * Sv[ns].y + bev.y;
        Tv[ns].z = (bv.z - mv.z) * Sv[ns].z + bev.z;
        Tv[ns].w = (bv.w - mv.w) * Sv[ns].w + bev.w;
    }
    #pragma unroll
    for (int mi = 0; mi < MW; ++mi) {
        int vD = vwave + mi * 16 + lr;
        int ow = vD % OUTS; int u1 = vD / OUTS;
        int oh = u1 % OUTS; int u2 = u1 / OUTS;
        int od = u2 % OUTS; int n = u2 / OUTS;
        unsigned short* yp =
            y + ((((size_t)n * OUTS + od) * OUTS + oh) * OUTS + ow) * COUT + gCoutBase;
        #pragma unroll
        for (int ns = 0; ns < NSW; ++ns) {
            float v0 = fmaxf(acc[mi][ns][0] * Sv[ns].x + Tv[ns].x, 0.f);
            float v1 = fmaxf(acc[mi][ns][1] * Sv[ns].y + Tv[ns].y, 0.f);
            float v2 = fmaxf(acc[mi][ns][2] * Sv[ns].z + Tv[ns].z, 0.f);
            float v3 = fmaxf(acc[mi][ns][3] * Sv[ns].w + Tv[ns].w, 0.f);
            uint2 uu;
            uu.x = cvtpk(v0, v1);
            uu.y = cvtpk(v2, v3);
            *reinterpret_cast<uint2*>(yp + ns * 16 + sg * 4) = uu;
        }
    }
}

// ---------------- Head: mean pool + 1x1 conv + BN/ReLU + 1x1 conv + top2 softmax
__global__ __launch_bounds__(256) void head_kernel(
    const unsigned short* __restrict__ x4,
    const float* __restrict__ w1k, const float* __restrict__ w1b,
    const float* __restrict__ wg,  const float* __restrict__ wbe,
    const float* __restrict__ wm,  const float* __restrict__ wv,
    const float* __restrict__ w2k, const float* __restrict__ w2b,
    float* __restrict__ out)
{
    __shared__ float part[8][256];
    __shared__ float h[256];
    __shared__ float r[256];
    __shared__ float logits[8];

    const int n = blockIdx.x;
    const int t = threadIdx.x;
    const int c8 = t & 31;
    const int pg = t >> 5;

    const unsigned short* xb = x4 + (size_t)n * 216 * 256 + c8 * 8;
    float s[8] = {0.f, 0.f, 0.f, 0.f, 0.f, 0.f, 0.f, 0.f};
    for (int i = pg; i < 216; i += 8) {
        ushort8v v8 = *reinterpret_cast<const ushort8v*>(xb + (size_t)i * 256);
        #pragma unroll
        for (int j = 0; j < 8; ++j) s[j] += bf2f(v8[j]);
    }
    #pragma unroll
    for (int j = 0; j < 8; ++j) part[pg][c8 * 8 + j] = s[j];
    __syncthreads();

    float a = 0.f;
    #pragma unroll
    for (int gi = 0; gi < 8; ++gi) a += part[gi][t];
    h[t] = a * (1.0f / 216.0f);
    __syncthreads();

    float acc = w1b[t];
    #pragma unroll 4
    for (int ci = 0; ci < 256; ++ci) acc += h[ci] * w1k[ci * 256 + t];
    float sc = wg[t] * rsqrtf(wv[t] + BN_EPS);
    acc = (acc - wm[t]) * sc + wbe[t];
    r[t] = fmaxf(acc, 0.f);
    __syncthreads();

    if (t < 8) {
        float a2 = w2b[t];
        for (int ci = 0; ci < 256; ++ci) a2 += r[ci] * w2k[ci * 8 + t];
        logits[t] = a2;
    }
    __syncthreads();

    if (t == 0) {
        float m1 = -INFINITY, m2 = -INFINITY;
        for (int e = 0; e < 8; ++e) {
            float val = logits[e];
            if (val > m1) { m2 = m1; m1 = val; }
            else if (val > m2) { m2 = val; }
        }
        float thr = m2;
        float ex[8]; float sum = 0.f;
        for (int e = 0; e < 8; ++e) {
            float val = (logits[e] >= thr) ? logits[e] : -INFINITY;
            ex[e] = expf(val - m1);
            sum += ex[e];
        }
        float inv = 1.0f / sum;
        for (int e = 0; e < 8; ++e) out[n * 8 + e] = ex[e] * inv;
    }
}

extern "C" void kernel_launch(void* const* d_in, const int* in_sizes, int n_in,
                              void* d_out, int out_size, void* d_ws, size_t ws_size,
                              hipStream_t stream) {
    const float* x   = (const float*)d_in[0];
    const float* k0  = (const float*)d_in[1];
    const float* b0  = (const float*)d_in[2];
    const float* g0  = (const float*)d_in[3];
    const float* be0 = (const float*)d_in[4];
    const float* m0  = (const float*)d_in[5];
    const float* v0  = (const float*)d_in[6];
    const float* k1  = (const float*)d_in[7];
    const float* b1  = (const float*)d_in[8];
    const float* g1  = (const float*)d_in[9];
    const float* be1 = (const float*)d_in[10];
    const float* m1  = (const float*)d_in[11];
    const float* v1  = (const float*)d_in[12];
    const float* k2  = (const float*)d_in[13];
    const float* b2  = (const float*)d_in[14];
    const float* g2  = (const float*)d_in[15];
    const float* be2 = (const float*)d_in[16];
    const float* m2  = (const float*)d_in[17];
    const float* v2  = (const float*)d_in[18];
    const float* k3  = (const float*)d_in[19];
    const float* b3  = (const float*)d_in[20];
    const float* g3  = (const float*)d_in[21];
    const float* be3 = (const float*)d_in[22];
    const float* m3  = (const float*)d_in[23];
    const float* v3  = (const float*)d_in[24];
    const float* w1k = (const float*)d_in[25];
    const float* w1b = (const float*)d_in[26];
    const float* wg  = (const float*)d_in[27];
    const float* wbe = (const float*)d_in[28];
    const float* wm  = (const float*)d_in[29];
    const float* wv  = (const float*)d_in[30];
    const float* w2k = (const float*)d_in[31];
    const float* w2b = (const float*)d_in[32];

    unsigned short* x1  = (unsigned short*)d_ws;
    unsigned short* x2  = x1 + 56623104;
    unsigned short* x3  = x2 + 14155776;
    unsigned short* x4  = x3 + 3538944;
    unsigned short* Wt1 = x4 + 884736;
    unsigned short* Wt2 = Wt1 + 55296;
    unsigned short* Wt3 = Wt2 + 221184;
    unsigned short* zp  = Wt3 + 884736;    // 1KB zero page
    unsigned short* W0f = zp + 512;        // conv0 B table, K=64 layout (4KB)

    wprep_all<<<568, 256, 0, stream>>>(k0, k1, k2, k3, W0f, Wt1, Wt2, Wt3, zp);
    conv0_lds<<<6912, 256, 0, stream>>>(x, W0f, (const float*)zp, b0, g0, be0, m0, v0, x1);
    conv_mfma_bg<32, 64, 48, 24, 2, 4, 1, 1, 1><<<1728, 256, 0, stream>>>(x1, Wt1, zp, b1, g1, be1, m1, v1, x2);
    conv_mfma_bg<64, 128, 24, 12, 1, 4, 2, 1, 1><<<864, 256, 0, stream>>>(x2, Wt2, zp, b2, g2, be2, m2, v2, x3);
    conv_mfma_bg<128, 256, 12, 6, 1, 1, 4, 4, 2><<<864, 256, 0, stream>>>(x3, Wt3, zp, b3, g3, be3, m3, v3, x4);
    head_kernel<<<16, 256, 0, stream>>>(x4, w1k, w1b, wg, wbe, wm, wv, w2k, w2b, (float*)d_out);
}

// Round 18
// 171.133 us; speedup vs baseline: 1.1889x; 1.1889x over previous
//
#include <hip/hip_runtime.h>
#include <math.h>

#define BN_EPS 1e-3f

typedef __attribute__((ext_vector_type(8))) unsigned short ushort8v;
typedef __attribute__((ext_vector_type(8))) short short8v;
typedef __attribute__((ext_vector_type(4))) float f32x4;
typedef __attribute__((ext_vector_type(4))) unsigned int uint4v;

__device__ __forceinline__ float4 f4load(const float* p) {
    return *reinterpret_cast<const float4*>(p);
}
__device__ __forceinline__ float bf2f(unsigned short u) {
    union { unsigned int i; float f; } w; w.i = ((unsigned int)u) << 16; return w.f;
}
__device__ __forceinline__ unsigned short f2bf(float f) {
    union { float fv; unsigned int i; } w; w.fv = f;
    unsigned int lsb = (w.i >> 16) & 1u;
    w.i += 0x7fffu + lsb;             // round-to-nearest-even
    return (unsigned short)(w.i >> 16);
}
// HW packed convert: returns [bf16(hi)<<16 | bf16(lo)] (RTNE)
__device__ __forceinline__ unsigned cvtpk(float lo, float hi) {
    unsigned r;
    asm("v_cvt_pk_bf16_f32 %0, %1, %2" : "=v"(r) : "v"(lo), "v"(hi));
    return r;
}
template<int N> __device__ __forceinline__ void waitv() {
    asm volatile("s_waitcnt vmcnt(%0)" :: "n"(N) : "memory");
}
// bijective XCD swizzle (grid % 8 == 0): blocks 0..n/8-1 -> XCD0, etc.
__device__ __forceinline__ int xcd_swz(int bid, int nwg) {
    return (bid & 7) * (nwg >> 3) + (bid >> 3);
}

#define GLOAD_LDS16(g, l)                                                     \
    __builtin_amdgcn_global_load_lds(                                         \
        (const __attribute__((address_space(1))) void*)(const void*)(g),      \
        (__attribute__((address_space(3))) void*)(void*)(l), 16, 0, 0)

// ---------------- Weight prep: k[tap][cin][cout] f32 ->
// frag-order Wt[it][nsg][lane][8] bf16; block 567 builds conv0 B-table
// (K=64 kd-plane-per-sg layout) + zero page.
template<int CIN, int COUT>
__device__ __forceinline__ void wprep_body(
    const float* __restrict__ k, unsigned short* __restrict__ wt, int blk)
{
    constexpr int NS = COUT / 16;
    constexpr int KS = CIN / 32;
    int idx = blk * 256 + (int)threadIdx.x;
    if (idx >= 27 * KS * NS * 64) return;
    int lane = idx & 63;
    int nsg  = (idx >> 6) % NS;
    int it   = idx / (64 * NS);
    int tap  = it / KS;
    int ks   = it - tap * KS;
    int sg = lane >> 4, lr = lane & 15;
    int cout = nsg * 16 + lr;
    ushort8v o;
    #pragma unroll
    for (int j = 0; j < 8; ++j) {
        int ci = ks * 32 + sg * 8 + j;
        o[j] = f2bf(k[(size_t)(tap * CIN + ci) * COUT + cout]);
    }
    *reinterpret_cast<ushort8v*>(wt + (size_t)idx * 8) = o;
}

__global__ __launch_bounds__(256) void wprep_all(
    const float* __restrict__ k0,
    const float* __restrict__ k1, const float* __restrict__ k2, const float* __restrict__ k3,
    unsigned short* __restrict__ w0f,
    unsigned short* __restrict__ w1, unsigned short* __restrict__ w2, unsigned short* __restrict__ w3,
    unsigned short* __restrict__ zp)
{
    int b = blockIdx.x;
    if (b < 27)       wprep_body<32, 64>(k1, w1, b);
    else if (b < 135) wprep_body<64, 128>(k2, w2, b - 27);
    else if (b < 567) wprep_body<128, 256>(k3, w3, b - 135);
    else {
        reinterpret_cast<unsigned int*>(zp)[threadIdx.x] = 0u;   // 1KB zero page
        {
            int t = (int)threadIdx.x;
            int lane = t & 63;
            int mf = (t >> 6) & 1;
            int ns = t >> 7;
            int sg = lane >> 4, lr = lane & 15;
            ushort8v o;
            #pragma unroll
            for (int j = 0; j < 8; ++j) {
                int jj = mf * 8 + j;
                bool valid = (sg < 3) && (jj < 9);
                int tap = sg * 9 + jj;
                o[j] = valid ? f2bf(k0[tap * 32 + ns * 16 + lr]) : (unsigned short)0;
            }
            *reinterpret_cast<ushort8v*>(w0f + (size_t)t * 8) = o;
        }
    }
}

// ---------------- Block 0: LDS-tiled im2col MFMA, kd-plane-per-sg K layout.
// Swapped operands (D = W·X): each lane holds 4 consecutive couts -> 8B stores.
__global__ __launch_bounds__(256) void conv0_lds(
    const float* __restrict__ x, const unsigned short* __restrict__ w0f,
    const float* __restrict__ zf,
    const float* __restrict__ b, const float* __restrict__ g,
    const float* __restrict__ be, const float* __restrict__ m,
    const float* __restrict__ v, unsigned short* __restrict__ y)
{
    __shared__ __attribute__((aligned(16))) float tile[81 * 36];  // 11664 B

    const int l   = threadIdx.x & 63;
    const int wid = threadIdx.x >> 6;
    const int sg  = l >> 4;
    const int lr  = l & 15;

    int bb = xcd_swz(blockIdx.x, 6912);
    const int owt = bb % 3;  bb /= 3;
    const int oht = bb % 12; bb /= 12;
    const int odt = bb % 12; const int n = bb / 12;

    const int id0 = odt * 8, ih0 = oht * 8, iw0 = owt * 32;

    // ---- stage: 81 rows x 9 chunks of 16B = 729 chunks
    #pragma unroll
    for (int q0 = 0; q0 < 729; q0 += 256) {
        int qq = q0 + wid * 64;            // wave-uniform LDS chunk base
        int q  = qq + l;
        if (qq < 729 && q < 729) {
            int row = q / 9, c = q - row * 9;
            int dd = row / 9, hh = row - dd * 9;
            int id = id0 + dd, ih = ih0 + hh;
            const float* src =
                (id < 96 && ih < 96 && (c < 8 || iw0 + 32 < 96))
                ? x + ((size_t)(n * 96 + id) * 96 + ih) * 96 + iw0 + c * 4
                : zf;
            GLOAD_LDS16(src, (char*)tile + (size_t)qq * 16);
        }
    }
    __syncthreads();

    const short8v B00 = *(const short8v*)(w0f + (size_t)(0 * 64 + l) * 8);
    const short8v B01 = *(const short8v*)(w0f + (size_t)(1 * 64 + l) * 8);
    const short8v B10 = *(const short8v*)(w0f + (size_t)(2 * 64 + l) * 8);
    const short8v B11 = *(const short8v*)(w0f + (size_t)(3 * 64 + l) * 8);

    // ---- per-lane gather: 9 rows of kd-plane (sg), cols 2lr..2lr+2
    float rc[9][3];
    {
        int dcl = (sg < 3) ? (2 * wid + sg) : 0;   // sg==3: harmless (W=0)
        const float* rb = tile + (size_t)(dcl * 9) * 36 + 2 * lr;
        #pragma unroll
        for (int r = 0; r < 9; ++r) {
            float2 lo = *reinterpret_cast<const float2*>(rb + r * 36);
            rc[r][0] = lo.x; rc[r][1] = lo.y;
            rc[r][2] = rb[r * 36 + 2];
        }
    }

    f32x4 acc[4][2];
    #pragma unroll
    for (int mi = 0; mi < 4; ++mi) {
        acc[mi][0] = (f32x4){0.f, 0.f, 0.f, 0.f};
        acc[mi][1] = (f32x4){0.f, 0.f, 0.f, 0.f};
    }

    #pragma unroll
    for (int mi = 0; mi < 4; ++mi) {
        const int h0 = 2 * mi;
        uint4v au0;
        au0[0] = cvtpk(rc[h0][0],     rc[h0][1]);
        au0[1] = cvtpk(rc[h0][2],     rc[h0 + 1][0]);
        au0[2] = cvtpk(rc[h0 + 1][1], rc[h0 + 1][2]);
        au0[3] = cvtpk(rc[h0 + 2][0], rc[h0 + 2][1]);
        short8v a0 = __builtin_bit_cast(short8v, au0);
        uint4v au1;
        au1[0] = cvtpk(rc[h0 + 2][2], 0.f);
        au1[1] = 0; au1[2] = 0; au1[3] = 0;
        short8v a1 = __builtin_bit_cast(short8v, au1);
        acc[mi][0] = __builtin_amdgcn_mfma_f32_16x16x32_bf16(B00, a0, acc[mi][0], 0, 0, 0);
        acc[mi][0] = __builtin_amdgcn_mfma_f32_16x16x32_bf16(B01, a1, acc[mi][0], 0, 0, 0);
        acc[mi][1] = __builtin_amdgcn_mfma_f32_16x16x32_bf16(B10, a0, acc[mi][1], 0, 0, 0);
        acc[mi][1] = __builtin_amdgcn_mfma_f32_16x16x32_bf16(B11, a1, acc[mi][1], 0, 0, 0);
    }

    float4 Sv[2], Tv[2];
    #pragma unroll
    for (int ns = 0; ns < 2; ++ns) {
        int c0 = ns * 16 + sg * 4;
        float4 gv = f4load(g + c0), vv = f4load(v + c0);
        float4 bv = f4load(b + c0), mv = f4load(m + c0), bev = f4load(be + c0);
        Sv[ns].x = gv.x * rsqrtf(vv.x + BN_EPS);
        Sv[ns].y = gv.y * rsqrtf(vv.y + BN_EPS);
        Sv[ns].z = gv.z * rsqrtf(vv.z + BN_EPS);
        Sv[ns].w = gv.w * rsqrtf(vv.w + BN_EPS);
        Tv[ns].x = (bv.x - mv.x) * Sv[ns].x + bev.x;
        Tv[ns].y = (bv.y - mv.y) * Sv[ns].y + bev.y;
        Tv[ns].z = (bv.z - mv.z) * Sv[ns].z + bev.z;
        Tv[ns].w = (bv.w - mv.w) * Sv[ns].w + bev.w;
    }
    const int odG = odt * 4 + wid;
    const int owG = owt * 16 + lr;
    #pragma unroll
    for (int mi = 0; mi < 4; ++mi) {
        int oh = oht * 4 + mi;
        unsigned short* yp =
            y + (((size_t)(n * 48 + odG) * 48 + oh) * 48 + owG) * 32;
        #pragma unroll
        for (int ns = 0; ns < 2; ++ns) {
            float v0 = fmaxf(acc[mi][ns][0] * Sv[ns].x + Tv[ns].x, 0.f);
            float v1 = fmaxf(acc[mi][ns][1] * Sv[ns].y + Tv[ns].y, 0.f);
            float v2 = fmaxf(acc[mi][ns][2] * Sv[ns].z + Tv[ns].z, 0.f);
            float v3 = fmaxf(acc[mi][ns][3] * Sv[ns].w + Tv[ns].w, 0.f);
            uint2 uu;
            uu.x = cvtpk(v0, v1);
            uu.y = cvtpk(v2, v3);
            *reinterpret_cast<uint2*>(yp + ns * 16 + sg * 4) = uu;
        }
    }
}

// ---------------- MFMA implicit-GEMM conv: 4-buffer depth-3 pipeline (R16),
// counted vmcnt + raw s_barrier; coalesced swizzled A-staging; swapped
// operands (D = W·X) -> 8B contiguous epilogue stores; + XCD block swizzle.
template<int CIN, int COUT, int INS, int OUTS, int MW, int NSW, int NH,
         int CSPLIT, int KU, int NWG>
__global__ __launch_bounds__(256, 2) void conv_mfma_lds(
    const unsigned short* __restrict__ x, const unsigned short* __restrict__ wt,
    const unsigned short* __restrict__ zp,
    const float* __restrict__ b, const float* __restrict__ g,
    const float* __restrict__ be, const float* __restrict__ m,
    const float* __restrict__ v, unsigned short* __restrict__ y)
{
    constexpr int NSfull = COUT / 16;
    constexpr int NSB = NSW * NH;
    constexpr int KS = CIN / 32;
    constexpr int NITK = 27 * KS;
    constexpr int NIT = NITK / KU;
    constexpr int MGROUPS = 4 / NH;
    constexpr int MTILE = MGROUPS * MW * 16;
    constexpr int BSTEP = NSB * KU * 1024;
    constexpr int ASTEP = MGROUPS * MW * KU * 1024;
    constexpr int STRIDE = BSTEP + ASTEP;
    constexpr int BL = (NSB * KU) / 4;
    constexpr int AL = MW * KU;
    static_assert(NSB * CSPLIT == NSfull && NITK % KU == 0 && (NSB * KU) % 4 == 0, "tiling");
    static_assert(NIT >= 3, "pipeline depth");

    __shared__ __attribute__((aligned(16))) char lds[4 * STRIDE];

    const int l   = threadIdx.x & 63;
    const int wid = threadIdx.x >> 6;
    const int sg  = l >> 4;
    const int lr  = l & 15;

    const int sbid   = xcd_swz(blockIdx.x, NWG);
    const int mblk   = sbid / CSPLIT;
    const int cchunk = sbid % CSPLIT;
    const int mgroup = wid / NH;
    const int ngroup = wid % NH;
    const int gCoutBase = (cchunk * NSB + ngroup * NSW) * 16;
    const int vwave = mblk * MTILE + mgroup * MW * 16;

    // Staging-side lane map: lane l fetches voxel (l>>2), cin-slice
    // ((l&3) - (l>>3)) & 3.
    const int vvS = l >> 2;
    const int ssS = ((l & 3) - (l >> 3)) & 3;

    const unsigned short* ap0[MW];
    unsigned smask[MW];
    #pragma unroll
    for (int mi = 0; mi < MW; ++mi) {
        int vA = vwave + mi * 16 + vvS;
        int owA = vA % OUTS; int t1 = vA / OUTS;
        int ohA = t1 % OUTS; int t2 = t1 / OUTS;
        int odA = t2 % OUTS; int nA = t2 / OUTS;
        ap0[mi] = x + ((((size_t)nA * INS + 2 * odA) * INS + 2 * ohA) * INS + 2 * owA) * CIN + ssS * 8;
        smask[mi] = ((odA == OUTS - 1) ? 0x07FC0000u : 0u)
                  | ((ohA == OUTS - 1) ? 0x070381C0u : 0u)
                  | ((owA == OUTS - 1) ? 0x04924924u : 0u);
    }

    const unsigned short* zpl = (const unsigned short*)((const char*)zp + l * 16);
    // Read-side inverse slot: lane (sg,lr) -> slot lr*4 + ((sg+(lr>>1))&3)
    const int slotA = (lr * 4 + ((sg + (lr >> 1)) & 3)) * 16;

    f32x4 acc[MW][NSW];
    #pragma unroll
    for (int mi = 0; mi < MW; ++mi)
        #pragma unroll
        for (int ns = 0; ns < NSW; ++ns) acc[mi][ns] = (f32x4){0.f, 0.f, 0.f, 0.f};

    auto stage = [&](int ito, int p) {
        char* dst = &lds[p * STRIDE];
        #pragma unroll
        for (int c = 0; c < BL; ++c) {
            int idx  = c * 256 + (int)threadIdx.x;
            int lane = idx & 63;
            int sub  = idx >> 6;
            int u    = sub / NSB;
            int grp  = sub % NSB;
            int it   = ito * KU + u;
            const unsigned short* src =
                wt + ((size_t)(it * NSfull + cchunk * NSB + grp) * 64 + lane) * 8;
            GLOAD_LDS16(src, dst + sub * 1024);
        }
        if (ngroup == 0) {
            #pragma unroll
            for (int u = 0; u < KU; ++u) {
                int it = ito * KU + u;
                int tap = (KS == 1) ? it : it / KS;
                int ks  = (KS == 1) ? 0  : it - tap * KS;
                int kd = tap / 9, r9 = tap - kd * 9, kh = r9 / 3, kw = r9 - kh * 3;
                size_t aoff = (size_t)((kd * INS + kh) * INS + kw) * CIN + ks * 32;
                #pragma unroll
                for (int mi = 0; mi < MW; ++mi) {
                    const unsigned short* ga =
                        ((smask[mi] >> tap) & 1u) ? zpl : (ap0[mi] + aoff);
                    GLOAD_LDS16(ga, dst + BSTEP + ((mgroup * MW + mi) * KU + u) * 1024);
                }
            }
        }
    };

    auto computestep = [&](const char* buf) {
        #pragma unroll
        for (int u = 0; u < KU; ++u) {
            short8v Bf[NSW], Af[MW];
            #pragma unroll
            for (int ns = 0; ns < NSW; ++ns)
                Bf[ns] = *(const short8v*)(buf + (u * NSB + ngroup * NSW + ns) * 1024 + l * 16);
            #pragma unroll
            for (int mi = 0; mi < MW; ++mi)
                Af[mi] = *(const short8v*)(buf + BSTEP + ((mgroup * MW + mi) * KU + u) * 1024 + slotA);
            #pragma unroll
            for (int mi = 0; mi < MW; ++mi)
                #pragma unroll
                for (int ns = 0; ns < NSW; ++ns)
                    acc[mi][ns] = __builtin_amdgcn_mfma_f32_16x16x32_bf16(Bf[ns], Af[mi], acc[mi][ns], 0, 0, 0);
        }
    };

    // depth-3 pipeline: 3 stages in flight, one barrier per iteration
    stage(0, 0);
    stage(1, 1);
    stage(2, 2);
    #pragma unroll 1
    for (int ito = 0; ito < NIT - 2; ++ito) {
        if (ngroup == 0) waitv<2 * (BL + AL)>(); else waitv<2 * BL>();
        __builtin_amdgcn_s_barrier();
        asm volatile("" ::: "memory");
        if (ito + 3 < NIT) stage(ito + 3, (ito + 3) & 3);
        computestep(&lds[(ito & 3) * STRIDE]);
    }
    // iter NIT-2: only stage NIT-1 still in flight
    if (ngroup == 0) waitv<BL + AL>(); else waitv<BL>();
    __builtin_amdgcn_s_barrier();
    asm volatile("" ::: "memory");
    computestep(&lds[((NIT - 2) & 3) * STRIDE]);
    // iter NIT-1: drain
    waitv<0>();
    __builtin_amdgcn_s_barrier();
    asm volatile("" ::: "memory");
    computestep(&lds[((NIT - 1) & 3) * STRIDE]);

    // epilogue: lane holds couts gCoutBase+ns*16+sg*4..+3 for voxel
    // vwave+mi*16+lr -> one 8B store per (mi,ns).
    float4 Sv[NSW], Tv[NSW];
    #pragma unroll
    for (int ns = 0; ns < NSW; ++ns) {
        int c0 = gCoutBase + ns * 16 + sg * 4;
        float4 gv = f4load(g + c0), vv = f4load(v + c0);
        float4 bv = f4load(b + c0), mv = f4load(m + c0), bev = f4load(be + c0);
        Sv[ns].x = gv.x * rsqrtf(vv.x + BN_EPS);
        Sv[ns].y = gv.y * rsqrtf(vv.y + BN_EPS);
        Sv[ns].z = gv.z * rsqrtf(vv.z + BN_EPS);
        Sv[ns].w = gv.w * rsqrtf(vv.w + BN_EPS);
        Tv[ns].x = (bv.x - mv.x) * Sv[ns].x + bev.x;
        Tv[ns].y = (bv.y - mv.y) * Sv[ns].y + bev.y;
        Tv[ns].z = (bv.z - mv.z) * Sv[ns].z + bev.z;
        Tv[ns].w = (bv.w - mv.w) * Sv[ns].w + bev.w;
    }
    #pragma unroll
    for (int mi = 0; mi < MW; ++mi) {
        int vD = vwave + mi * 16 + lr;
        int ow = vD % OUTS; int u1 = vD / OUTS;
        int oh = u1 % OUTS; int u2 = u1 / OUTS;
        int od = u2 % OUTS; int n = u2 / OUTS;
        unsigned short* yp =
            y + ((((size_t)n * OUTS + od) * OUTS + oh) * OUTS + ow) * COUT + gCoutBase;
        #pragma unroll
        for (int ns = 0; ns < NSW; ++ns) {
            float v0 = fmaxf(acc[mi][ns][0] * Sv[ns].x + Tv[ns].x, 0.f);
            float v1 = fmaxf(acc[mi][ns][1] * Sv[ns].y + Tv[ns].y, 0.f);
            float v2 = fmaxf(acc[mi][ns][2] * Sv[ns].z + Tv[ns].z, 0.f);
            float v3 = fmaxf(acc[mi][ns][3] * Sv[ns].w + Tv[ns].w, 0.f);
            uint2 uu;
            uu.x = cvtpk(v0, v1);
            uu.y = cvtpk(v2, v3);
            *reinterpret_cast<uint2*>(yp + ns * 16 + sg * 4) = uu;
        }
    }
}

// ---------------- Head: mean pool + 1x1 conv + BN/ReLU + 1x1 conv + top2 softmax
__global__ __launch_bounds__(256) void head_kernel(
    const unsigned short* __restrict__ x4,
    const float* __restrict__ w1k, const float* __restrict__ w1b,
    const float* __restrict__ wg,  const float* __restrict__ wbe,
    const float* __restrict__ wm,  const float* __restrict__ wv,
    const float* __restrict__ w2k, const float* __restrict__ w2b,
    float* __restrict__ out)
{
    __shared__ float part[8][256];
    __shared__ float h[256];
    __shared__ float r[256];
    __shared__ float logits[8];

    const int n = blockIdx.x;
    const int t = threadIdx.x;
    const int c8 = t & 31;
    const int pg = t >> 5;

    const unsigned short* xb = x4 + (size_t)n * 216 * 256 + c8 * 8;
    float s[8] = {0.f, 0.f, 0.f, 0.f, 0.f, 0.f, 0.f, 0.f};
    for (int i = pg; i < 216; i += 8) {
        ushort8v v8 = *reinterpret_cast<const ushort8v*>(xb + (size_t)i * 256);
        #pragma unroll
        for (int j = 0; j < 8; ++j) s[j] += bf2f(v8[j]);
    }
    #pragma unroll
    for (int j = 0; j < 8; ++j) part[pg][c8 * 8 + j] = s[j];
    __syncthreads();

    float a = 0.f;
    #pragma unroll
    for (int gi = 0; gi < 8; ++gi) a += part[gi][t];
    h[t] = a * (1.0f / 216.0f);
    __syncthreads();

    float acc = w1b[t];
    #pragma unroll 4
    for (int ci = 0; ci < 256; ++ci) acc += h[ci] * w1k[ci * 256 + t];
    float sc = wg[t] * rsqrtf(wv[t] + BN_EPS);
    acc = (acc - wm[t]) * sc + wbe[t];
    r[t] = fmaxf(acc, 0.f);
    __syncthreads();

    if (t < 8) {
        float a2 = w2b[t];
        for (int ci = 0; ci < 256; ++ci) a2 += r[ci] * w2k[ci * 8 + t];
        logits[t] = a2;
    }
    __syncthreads();

    if (t == 0) {
        float m1 = -INFINITY, m2 = -INFINITY;
        for (int e = 0; e < 8; ++e) {
            float val = logits[e];
            if (val > m1) { m2 = m1; m1 = val; }
            else if (val > m2) { m2 = val; }
        }
        float thr = m2;
        float ex[8]; float sum = 0.f;
        for (int e = 0; e < 8; ++e) {
            float val = (logits[e] >= thr) ? logits[e] : -INFINITY;
            ex[e] = expf(val - m1);
            sum += ex[e];
        }
        float inv = 1.0f / sum;
        for (int e = 0; e < 8; ++e) out[n * 8 + e] = ex[e] * inv;
    }
}

extern "C" void kernel_launch(void* const* d_in, const int* in_sizes, int n_in,
                              void* d_out, int out_size, void* d_ws, size_t ws_size,
                              hipStream_t stream) {
    const float* x   = (const float*)d_in[0];
    const float* k0  = (const float*)d_in[1];
    const float* b0  = (const float*)d_in[2];
    const float* g0  = (const float*)d_in[3];
    const float* be0 = (const float*)d_in[4];
    const float* m0  = (const float*)d_in[5];
    const float* v0  = (const float*)d_in[6];
    const float* k1  = (const float*)d_in[7];
    const float* b1  = (const float*)d_in[8];
    const float* g1  = (const float*)d_in[9];
    const float* be1 = (const float*)d_in[10];
    const float* m1  = (const float*)d_in[11];
    const float* v1  = (const float*)d_in[12];
    const float* k2  = (const float*)d_in[13];
    const float* b2  = (const float*)d_in[14];
    const float* g2  = (const float*)d_in[15];
    const float* be2 = (const float*)d_in[16];
    const float* m2  = (const float*)d_in[17];
    const float* v2  = (const float*)d_in[18];
    const float* k3  = (const float*)d_in[19];
    const float* b3  = (const float*)d_in[20];
    const float* g3  = (const float*)d_in[21];
    const float* be3 = (const float*)d_in[22];
    const float* m3  = (const float*)d_in[23];
    const float* v3  = (const float*)d_in[24];
    const float* w1k = (const float*)d_in[25];
    const float* w1b = (const float*)d_in[26];
    const float* wg  = (const float*)d_in[27];
    const float* wbe = (const float*)d_in[28];
    const float* wm  = (const float*)d_in[29];
    const float* wv  = (const float*)d_in[30];
    const float* w2k = (const float*)d_in[31];
    const float* w2b = (const float*)d_in[32];

    unsigned short* x1  = (unsigned short*)d_ws;
    unsigned short* x2  = x1 + 56623104;
    unsigned short* x3  = x2 + 14155776;
    unsigned short* x4  = x3 + 3538944;
    unsigned short* Wt1 = x4 + 884736;
    unsigned short* Wt2 = Wt1 + 55296;
    unsigned short* Wt3 = Wt2 + 221184;
    unsigned short* zp  = Wt3 + 884736;    // 1KB zero page
    unsigned short* W0f = zp + 512;        // conv0 B table, K=64 layout (4KB)

    wprep_all<<<568, 256, 0, stream>>>(k0, k1, k2, k3, W0f, Wt1, Wt2, Wt3, zp);
    conv0_lds<<<6912, 256, 0, stream>>>(x, W0f, (const float*)zp, b0, g0, be0, m0, v0, x1);
    conv_mfma_lds<32, 64, 48, 24, 2, 4, 1, 1, 1, 1728><<<1728, 256, 0, stream>>>(x1, Wt1, zp, b1, g1, be1, m1, v1, x2);
    conv_mfma_lds<64, 128, 24, 12, 1, 4, 2, 1, 1, 864><<<864, 256, 0, stream>>>(x2, Wt2, zp, b2, g2, be2, m2, v2, x3);
    conv_mfma_lds<128, 256, 12, 6, 1, 1, 4, 4, 2, 864><<<864, 256, 0, stream>>>(x3, Wt3, zp, b3, g3, be3, m3, v3, x4);
    head_kernel<<<16, 256, 0, stream>>>(x4, w1k, w1b, wg, wbe, wm, wv, w2k, w2b, (float*)d_out);
}

// Round 19
// 168.005 us; speedup vs baseline: 1.2110x; 1.0186x over previous
//
#include <hip/hip_runtime.h>
#include <math.h>

#define BN_EPS 1e-3f

typedef __attribute__((ext_vector_type(8))) unsigned short ushort8v;
typedef __attribute__((ext_vector_type(8))) short short8v;
typedef __attribute__((ext_vector_type(4))) float f32x4;
typedef __attribute__((ext_vector_type(4))) unsigned int uint4v;

__device__ __forceinline__ float4 f4load(const float* p) {
    return *reinterpret_cast<const float4*>(p);
}
__device__ __forceinline__ float bf2f(unsigned short u) {
    union { unsigned int i; float f; } w; w.i = ((unsigned int)u) << 16; return w.f;
}
__device__ __forceinline__ unsigned short f2bf(float f) {
    union { float fv; unsigned int i; } w; w.fv = f;
    unsigned int lsb = (w.i >> 16) & 1u;
    w.i += 0x7fffu + lsb;             // round-to-nearest-even
    return (unsigned short)(w.i >> 16);
}
// HW packed convert: returns [bf16(hi)<<16 | bf16(lo)] (RTNE)
__device__ __forceinline__ unsigned cvtpk(float lo, float hi) {
    unsigned r;
    asm("v_cvt_pk_bf16_f32 %0, %1, %2" : "=v"(r) : "v"(lo), "v"(hi));
    return r;
}
template<int N> __device__ __forceinline__ void waitv() {
    asm volatile("s_waitcnt vmcnt(%0)" :: "n"(N) : "memory");
}
// bijective XCD swizzle (grid % 8 == 0)
__device__ __forceinline__ int xcd_swz(int bid, int nwg) {
    return (bid & 7) * (nwg >> 3) + (bid >> 3);
}

#define GLOAD_LDS16(g, l)                                                     \
    __builtin_amdgcn_global_load_lds(                                         \
        (const __attribute__((address_space(1))) void*)(const void*)(g),      \
        (__attribute__((address_space(3))) void*)(void*)(l), 16, 0, 0)

// ---------------- Weight prep (unchanged from R18)
template<int CIN, int COUT>
__device__ __forceinline__ void wprep_body(
    const float* __restrict__ k, unsigned short* __restrict__ wt, int blk)
{
    constexpr int NS = COUT / 16;
    constexpr int KS = CIN / 32;
    int idx = blk * 256 + (int)threadIdx.x;
    if (idx >= 27 * KS * NS * 64) return;
    int lane = idx & 63;
    int nsg  = (idx >> 6) % NS;
    int it   = idx / (64 * NS);
    int tap  = it / KS;
    int ks   = it - tap * KS;
    int sg = lane >> 4, lr = lane & 15;
    int cout = nsg * 16 + lr;
    ushort8v o;
    #pragma unroll
    for (int j = 0; j < 8; ++j) {
        int ci = ks * 32 + sg * 8 + j;
        o[j] = f2bf(k[(size_t)(tap * CIN + ci) * COUT + cout]);
    }
    *reinterpret_cast<ushort8v*>(wt + (size_t)idx * 8) = o;
}

__global__ __launch_bounds__(256) void wprep_all(
    const float* __restrict__ k0,
    const float* __restrict__ k1, const float* __restrict__ k2, const float* __restrict__ k3,
    unsigned short* __restrict__ w0f,
    unsigned short* __restrict__ w1, unsigned short* __restrict__ w2, unsigned short* __restrict__ w3,
    unsigned short* __restrict__ zp)
{
    int b = blockIdx.x;
    if (b < 27)       wprep_body<32, 64>(k1, w1, b);
    else if (b < 135) wprep_body<64, 128>(k2, w2, b - 27);
    else if (b < 567) wprep_body<128, 256>(k3, w3, b - 135);
    else {
        reinterpret_cast<unsigned int*>(zp)[threadIdx.x] = 0u;   // 1KB zero page
        {
            int t = (int)threadIdx.x;
            int lane = t & 63;
            int mf = (t >> 6) & 1;
            int ns = t >> 7;
            int sg = lane >> 4, lr = lane & 15;
            ushort8v o;
            #pragma unroll
            for (int j = 0; j < 8; ++j) {
                int jj = mf * 8 + j;
                bool valid = (sg < 3) && (jj < 9);
                int tap = sg * 9 + jj;
                o[j] = valid ? f2bf(k0[tap * 32 + ns * 16 + lr]) : (unsigned short)0;
            }
            *reinterpret_cast<ushort8v*>(w0f + (size_t)t * 8) = o;
        }
    }
}

// ---------------- Block 0: LDS-tiled im2col MFMA, 2 tiles/block double-buffered.
// stage(t1) flies under compute(t0); counted vmcnt (768 chunks = exactly 3
// loads/thread/stage). Swapped operands (D = W·X) -> 8B contiguous stores.
__global__ __launch_bounds__(256) void conv0_p2(
    const float* __restrict__ x, const unsigned short* __restrict__ w0f,
    const float* __restrict__ zf,
    const float* __restrict__ b, const float* __restrict__ g,
    const float* __restrict__ be, const float* __restrict__ m,
    const float* __restrict__ v, unsigned short* __restrict__ y)
{
    __shared__ __attribute__((aligned(16))) float tile[2][3072];  // 2 x 12288B

    const int l   = threadIdx.x & 63;
    const int wid = threadIdx.x >> 6;
    const int sg  = l >> 4;
    const int lr  = l & 15;

    const int sbid = xcd_swz(blockIdx.x, 3456);

    const short8v B00 = *(const short8v*)(w0f + (size_t)(0 * 64 + l) * 8);
    const short8v B01 = *(const short8v*)(w0f + (size_t)(1 * 64 + l) * 8);
    const short8v B10 = *(const short8v*)(w0f + (size_t)(2 * 64 + l) * 8);
    const short8v B11 = *(const short8v*)(w0f + (size_t)(3 * 64 + l) * 8);

    float4 Sv[2], Tv[2];
    #pragma unroll
    for (int ns = 0; ns < 2; ++ns) {
        int c0 = ns * 16 + sg * 4;
        float4 gv = f4load(g + c0), vv = f4load(v + c0);
        float4 bv = f4load(b + c0), mv = f4load(m + c0), bev = f4load(be + c0);
        Sv[ns].x = gv.x * rsqrtf(vv.x + BN_EPS);
        Sv[ns].y = gv.y * rsqrtf(vv.y + BN_EPS);
        Sv[ns].z = gv.z * rsqrtf(vv.z + BN_EPS);
        Sv[ns].w = gv.w * rsqrtf(vv.w + BN_EPS);
        Tv[ns].x = (bv.x - mv.x) * Sv[ns].x + bev.x;
        Tv[ns].y = (bv.y - mv.y) * Sv[ns].y + bev.y;
        Tv[ns].z = (bv.z - mv.z) * Sv[ns].z + bev.z;
        Tv[ns].w = (bv.w - mv.w) * Sv[ns].w + bev.w;
    }

    auto stage = [&](int tid, int p) {
        int bb = tid;
        int owt = bb % 3;  bb /= 3;
        int oht = bb % 12; bb /= 12;
        int odt = bb % 12; int n = bb / 12;
        int id0 = odt * 8, ih0 = oht * 8, iw0 = owt * 32;
        char* dst = (char*)tile[p];
        #pragma unroll
        for (int q0 = 0; q0 < 768; q0 += 256) {
            int qq = q0 + wid * 64;
            int q  = qq + l;
            const float* src = zf;
            if (q < 729) {
                int row = q / 9, c = q - row * 9;
                int dd = row / 9, hh = row - dd * 9;
                int id = id0 + dd, ih = ih0 + hh;
                if (id < 96 && ih < 96 && (c < 8 || iw0 + 32 < 96))
                    src = x + ((size_t)(n * 96 + id) * 96 + ih) * 96 + iw0 + c * 4;
            }
            GLOAD_LDS16(src, dst + (size_t)qq * 16);
        }
    };

    auto compute = [&](int tid, int p) {
        int bb = tid;
        int owt = bb % 3;  bb /= 3;
        int oht = bb % 12; bb /= 12;
        int odt = bb % 12; int n = bb / 12;

        float rc[9][3];
        {
            int dcl = (sg < 3) ? (2 * wid + sg) : 0;   // sg==3: harmless (W=0)
            const float* rb = tile[p] + (size_t)(dcl * 9) * 36 + 2 * lr;
            #pragma unroll
            for (int r = 0; r < 9; ++r) {
                float2 lo = *reinterpret_cast<const float2*>(rb + r * 36);
                rc[r][0] = lo.x; rc[r][1] = lo.y;
                rc[r][2] = rb[r * 36 + 2];
            }
        }

        f32x4 acc[4][2];
        #pragma unroll
        for (int mi = 0; mi < 4; ++mi) {
            acc[mi][0] = (f32x4){0.f, 0.f, 0.f, 0.f};
            acc[mi][1] = (f32x4){0.f, 0.f, 0.f, 0.f};
        }
        #pragma unroll
        for (int mi = 0; mi < 4; ++mi) {
            const int h0 = 2 * mi;
            uint4v au0;
            au0[0] = cvtpk(rc[h0][0],     rc[h0][1]);
            au0[1] = cvtpk(rc[h0][2],     rc[h0 + 1][0]);
            au0[2] = cvtpk(rc[h0 + 1][1], rc[h0 + 1][2]);
            au0[3] = cvtpk(rc[h0 + 2][0], rc[h0 + 2][1]);
            short8v a0 = __builtin_bit_cast(short8v, au0);
            uint4v au1;
            au1[0] = cvtpk(rc[h0 + 2][2], 0.f);
            au1[1] = 0; au1[2] = 0; au1[3] = 0;
            short8v a1 = __builtin_bit_cast(short8v, au1);
            acc[mi][0] = __builtin_amdgcn_mfma_f32_16x16x32_bf16(B00, a0, acc[mi][0], 0, 0, 0);
            acc[mi][0] = __builtin_amdgcn_mfma_f32_16x16x32_bf16(B01, a1, acc[mi][0], 0, 0, 0);
            acc[mi][1] = __builtin_amdgcn_mfma_f32_16x16x32_bf16(B10, a0, acc[mi][1], 0, 0, 0);
            acc[mi][1] = __builtin_amdgcn_mfma_f32_16x16x32_bf16(B11, a1, acc[mi][1], 0, 0, 0);
        }

        const int odG = odt * 4 + wid;
        const int owG = owt * 16 + lr;
        #pragma unroll
        for (int mi = 0; mi < 4; ++mi) {
            int oh = oht * 4 + mi;
            unsigned short* yp =
                y + (((size_t)(n * 48 + odG) * 48 + oh) * 48 + owG) * 32;
            #pragma unroll
            for (int ns = 0; ns < 2; ++ns) {
                float v0 = fmaxf(acc[mi][ns][0] * Sv[ns].x + Tv[ns].x, 0.f);
                float v1 = fmaxf(acc[mi][ns][1] * Sv[ns].y + Tv[ns].y, 0.f);
                float v2 = fmaxf(acc[mi][ns][2] * Sv[ns].z + Tv[ns].z, 0.f);
                float v3 = fmaxf(acc[mi][ns][3] * Sv[ns].w + Tv[ns].w, 0.f);
                uint2 uu;
                uu.x = cvtpk(v0, v1);
                uu.y = cvtpk(v2, v3);
                *reinterpret_cast<uint2*>(yp + ns * 16 + sg * 4) = uu;
            }
        }
    };

    stage(2 * sbid, 0);
    stage(2 * sbid + 1, 1);
    // buf0 ready (3 loads of stage1 still in flight)
    waitv<3>();
    __builtin_amdgcn_s_barrier();
    asm volatile("" ::: "memory");
    compute(2 * sbid, 0);
    // stage1's 3 loads are the oldest; my 8 epilogue stores may be outstanding
    waitv<8>();
    __builtin_amdgcn_s_barrier();
    asm volatile("" ::: "memory");
    compute(2 * sbid + 1, 1);
}

// ---------------- MFMA implicit-GEMM conv (R18, unchanged)
template<int CIN, int COUT, int INS, int OUTS, int MW, int NSW, int NH,
         int CSPLIT, int KU, int NWG>
__global__ __launch_bounds__(256, 2) void conv_mfma_lds(
    const unsigned short* __restrict__ x, const unsigned short* __restrict__ wt,
    const unsigned short* __restrict__ zp,
    const float* __restrict__ b, const float* __restrict__ g,
    const float* __restrict__ be, const float* __restrict__ m,
    const float* __restrict__ v, unsigned short* __restrict__ y)
{
    constexpr int NSfull = COUT / 16;
    constexpr int NSB = NSW * NH;
    constexpr int KS = CIN / 32;
    constexpr int NITK = 27 * KS;
    constexpr int NIT = NITK / KU;
    constexpr int MGROUPS = 4 / NH;
    constexpr int MTILE = MGROUPS * MW * 16;
    constexpr int BSTEP = NSB * KU * 1024;
    constexpr int ASTEP = MGROUPS * MW * KU * 1024;
    constexpr int STRIDE = BSTEP + ASTEP;
    constexpr int BL = (NSB * KU) / 4;
    constexpr int AL = MW * KU;
    static_assert(NSB * CSPLIT == NSfull && NITK % KU == 0 && (NSB * KU) % 4 == 0, "tiling");
    static_assert(NIT >= 3, "pipeline depth");

    __shared__ __attribute__((aligned(16))) char lds[4 * STRIDE];

    const int l   = threadIdx.x & 63;
    const int wid = threadIdx.x >> 6;
    const int sg  = l >> 4;
    const int lr  = l & 15;

    const int sbid   = xcd_swz(blockIdx.x, NWG);
    const int mblk   = sbid / CSPLIT;
    const int cchunk = sbid % CSPLIT;
    const int mgroup = wid / NH;
    const int ngroup = wid % NH;
    const int gCoutBase = (cchunk * NSB + ngroup * NSW) * 16;
    const int vwave = mblk * MTILE + mgroup * MW * 16;

    const int vvS = l >> 2;
    const int ssS = ((l & 3) - (l >> 3)) & 3;

    const unsigned short* ap0[MW];
    unsigned smask[MW];
    #pragma unroll
    for (int mi = 0; mi < MW; ++mi) {
        int vA = vwave + mi * 16 + vvS;
        int owA = vA % OUTS; int t1 = vA / OUTS;
        int ohA = t1 % OUTS; int t2 = t1 / OUTS;
        int odA = t2 % OUTS; int nA = t2 / OUTS;
        ap0[mi] = x + ((((size_t)nA * INS + 2 * odA) * INS + 2 * ohA) * INS + 2 * owA) * CIN + ssS * 8;
        smask[mi] = ((odA == OUTS - 1) ? 0x07FC0000u : 0u)
                  | ((ohA == OUTS - 1) ? 0x070381C0u : 0u)
                  | ((owA == OUTS - 1) ? 0x04924924u : 0u);
    }

    const unsigned short* zpl = (const unsigned short*)((const char*)zp + l * 16);
    const int slotA = (lr * 4 + ((sg + (lr >> 1)) & 3)) * 16;

    f32x4 acc[MW][NSW];
    #pragma unroll
    for (int mi = 0; mi < MW; ++mi)
        #pragma unroll
        for (int ns = 0; ns < NSW; ++ns) acc[mi][ns] = (f32x4){0.f, 0.f, 0.f, 0.f};

    auto stage = [&](int ito, int p) {
        char* dst = &lds[p * STRIDE];
        #pragma unroll
        for (int c = 0; c < BL; ++c) {
            int idx  = c * 256 + (int)threadIdx.x;
            int lane = idx & 63;
            int sub  = idx >> 6;
            int u    = sub / NSB;
            int grp  = sub % NSB;
            int it   = ito * KU + u;
            const unsigned short* src =
                wt + ((size_t)(it * NSfull + cchunk * NSB + grp) * 64 + lane) * 8;
            GLOAD_LDS16(src, dst + sub * 1024);
        }
        if (ngroup == 0) {
            #pragma unroll
            for (int u = 0; u < KU; ++u) {
                int it = ito * KU + u;
                int tap = (KS == 1) ? it : it / KS;
                int ks  = (KS == 1) ? 0  : it - tap * KS;
                int kd = tap / 9, r9 = tap - kd * 9, kh = r9 / 3, kw = r9 - kh * 3;
                size_t aoff = (size_t)((kd * INS + kh) * INS + kw) * CIN + ks * 32;
                #pragma unroll
                for (int mi = 0; mi < MW; ++mi) {
                    const unsigned short* ga =
                        ((smask[mi] >> tap) & 1u) ? zpl : (ap0[mi] + aoff);
                    GLOAD_LDS16(ga, dst + BSTEP + ((mgroup * MW + mi) * KU + u) * 1024);
                }
            }
        }
    };

    auto computestep = [&](const char* buf) {
        #pragma unroll
        for (int u = 0; u < KU; ++u) {
            short8v Bf[NSW], Af[MW];
            #pragma unroll
            for (int ns = 0; ns < NSW; ++ns)
                Bf[ns] = *(const short8v*)(buf + (u * NSB + ngroup * NSW + ns) * 1024 + l * 16);
            #pragma unroll
            for (int mi = 0; mi < MW; ++mi)
                Af[mi] = *(const short8v*)(buf + BSTEP + ((mgroup * MW + mi) * KU + u) * 1024 + slotA);
            #pragma unroll
            for (int mi = 0; mi < MW; ++mi)
                #pragma unroll
                for (int ns = 0; ns < NSW; ++ns)
                    acc[mi][ns] = __builtin_amdgcn_mfma_f32_16x16x32_bf16(Bf[ns], Af[mi], acc[mi][ns], 0, 0, 0);
        }
    };

    stage(0, 0);
    stage(1, 1);
    stage(2, 2);
    #pragma unroll 1
    for (int ito = 0; ito < NIT - 2; ++ito) {
        if (ngroup == 0) waitv<2 * (BL + AL)>(); else waitv<2 * BL>();
        __builtin_amdgcn_s_barrier();
        asm volatile("" ::: "memory");
        if (ito + 3 < NIT) stage(ito + 3, (ito + 3) & 3);
        computestep(&lds[(ito & 3) * STRIDE]);
    }
    if (ngroup == 0) waitv<BL + AL>(); else waitv<BL>();
    __builtin_amdgcn_s_barrier();
    asm volatile("" ::: "memory");
    computestep(&lds[((NIT - 2) & 3) * STRIDE]);
    waitv<0>();
    __builtin_amdgcn_s_barrier();
    asm volatile("" ::: "memory");
    computestep(&lds[((NIT - 1) & 3) * STRIDE]);

    float4 Sv[NSW], Tv[NSW];
    #pragma unroll
    for (int ns = 0; ns < NSW; ++ns) {
        int c0 = gCoutBase + ns * 16 + sg * 4;
        float4 gv = f4load(g + c0), vv = f4load(v + c0);
        float4 bv = f4load(b + c0), mv = f4load(m + c0), bev = f4load(be + c0);
        Sv[ns].x = gv.x * rsqrtf(vv.x + BN_EPS);
        Sv[ns].y = gv.y * rsqrtf(vv.y + BN_EPS);
        Sv[ns].z = gv.z * rsqrtf(vv.z + BN_EPS);
        Sv[ns].w = gv.w * rsqrtf(vv.w + BN_EPS);
        Tv[ns].x = (bv.x - mv.x) * Sv[ns].x + bev.x;
        Tv[ns].y = (bv.y - mv.y) * Sv[ns].y + bev.y;
        Tv[ns].z = (bv.z - mv.z) * Sv[ns].z + bev.z;
        Tv[ns].w = (bv.w - mv.w) * Sv[ns].w + bev.w;
    }
    #pragma unroll
    for (int mi = 0; mi < MW; ++mi) {
        int vD = vwave + mi * 16 + lr;
        int ow = vD % OUTS; int u1 = vD / OUTS;
        int oh = u1 % OUTS; int u2 = u1 / OUTS;
        int od = u2 % OUTS; int n = u2 / OUTS;
        unsigned short* yp =
            y + ((((size_t)n * OUTS + od) * OUTS + oh) * OUTS + ow) * COUT + gCoutBase;
        #pragma unroll
        for (int ns = 0; ns < NSW; ++ns) {
            float v0 = fmaxf(acc[mi][ns][0] * Sv[ns].x + Tv[ns].x, 0.f);
            float v1 = fmaxf(acc[mi][ns][1] * Sv[ns].y + Tv[ns].y, 0.f);
            float v2 = fmaxf(acc[mi][ns][2] * Sv[ns].z + Tv[ns].z, 0.f);
            float v3 = fmaxf(acc[mi][ns][3] * Sv[ns].w + Tv[ns].w, 0.f);
            uint2 uu;
            uu.x = cvtpk(v0, v1);
            uu.y = cvtpk(v2, v3);
            *reinterpret_cast<uint2*>(yp + ns * 16 + sg * 4) = uu;
        }
    }
}

// ---------------- Head (unchanged)
__global__ __launch_bounds__(256) void head_kernel(
    const unsigned short* __restrict__ x4,
    const float* __restrict__ w1k, const float* __restrict__ w1b,
    const float* __restrict__ wg,  const float* __restrict__ wbe,
    const float* __restrict__ wm,  const float* __restrict__ wv,
    const float* __restrict__ w2k, const float* __restrict__ w2b,
    float* __restrict__ out)
{
    __shared__ float part[8][256];
    __shared__ float h[256];
    __shared__ float r[256];
    __shared__ float logits[8];

    const int n = blockIdx.x;
    const int t = threadIdx.x;
    const int c8 = t & 31;
    const int pg = t >> 5;

    const unsigned short* xb = x4 + (size_t)n * 216 * 256 + c8 * 8;
    float s[8] = {0.f, 0.f, 0.f, 0.f, 0.f, 0.f, 0.f, 0.f};
    for (int i = pg; i < 216; i += 8) {
        ushort8v v8 = *reinterpret_cast<const ushort8v*>(xb + (size_t)i * 256);
        #pragma unroll
        for (int j = 0; j < 8; ++j) s[j] += bf2f(v8[j]);
    }
    #pragma unroll
    for (int j = 0; j < 8; ++j) part[pg][c8 * 8 + j] = s[j];
    __syncthreads();

    float a = 0.f;
    #pragma unroll
    for (int gi = 0; gi < 8; ++gi) a += part[gi][t];
    h[t] = a * (1.0f / 216.0f);
    __syncthreads();

    float acc = w1b[t];
    #pragma unroll 4
    for (int ci = 0; ci < 256; ++ci) acc += h[ci] * w1k[ci * 256 + t];
    float sc = wg[t] * rsqrtf(wv[t] + BN_EPS);
    acc = (acc - wm[t]) * sc + wbe[t];
    r[t] = fmaxf(acc, 0.f);
    __syncthreads();

    if (t < 8) {
        float a2 = w2b[t];
        for (int ci = 0; ci < 256; ++ci) a2 += r[ci] * w2k[ci * 8 + t];
        logits[t] = a2;
    }
    __syncthreads();

    if (t == 0) {
        float m1 = -INFINITY, m2 = -INFINITY;
        for (int e = 0; e < 8; ++e) {
            float val = logits[e];
            if (val > m1) { m2 = m1; m1 = val; }
            else if (val > m2) { m2 = val; }
        }
        float thr = m2;
        float ex[8]; float sum = 0.f;
        for (int e = 0; e < 8; ++e) {
            float val = (logits[e] >= thr) ? logits[e] : -INFINITY;
            ex[e] = expf(val - m1);
            sum += ex[e];
        }
        float inv = 1.0f / sum;
        for (int e = 0; e < 8; ++e) out[n * 8 + e] = ex[e] * inv;
    }
}

extern "C" void kernel_launch(void* const* d_in, const int* in_sizes, int n_in,
                              void* d_out, int out_size, void* d_ws, size_t ws_size,
                              hipStream_t stream) {
    const float* x   = (const float*)d_in[0];
    const float* k0  = (const float*)d_in[1];
    const float* b0  = (const float*)d_in[2];
    const float* g0  = (const float*)d_in[3];
    const float* be0 = (const float*)d_in[4];
    const float* m0  = (const float*)d_in[5];
    const float* v0  = (const float*)d_in[6];
    const float* k1  = (const float*)d_in[7];
    const float* b1  = (const float*)d_in[8];
    const float* g1  = (const float*)d_in[9];
    const float* be1 = (const float*)d_in[10];
    const float* m1  = (const float*)d_in[11];
    const float* v1  = (const float*)d_in[12];
    const float* k2  = (const float*)d_in[13];
    const float* b2  = (const float*)d_in[14];
    const float* g2  = (const float*)d_in[15];
    const float* be2 = (const float*)d_in[16];
    const float* m2  = (const float*)d_in[17];
    const float* v2  = (const float*)d_in[18];
    const float* k3  = (const float*)d_in[19];
    const float* b3  = (const float*)d_in[20];
    const float* g3  = (const float*)d_in[21];
    const float* be3 = (const float*)d_in[22];
    const float* m3  = (const float*)d_in[23];
    const float* v3  = (const float*)d_in[24];
    const float* w1k = (const float*)d_in[25];
    const float* w1b = (const float*)d_in[26];
    const float* wg  = (const float*)d_in[27];
    const float* wbe = (const float*)d_in[28];
    const float* wm  = (const float*)d_in[29];
    const float* wv  = (const float*)d_in[30];
    const float* w2k = (const float*)d_in[31];
    const float* w2b = (const float*)d_in[32];

    unsigned short* x1  = (unsigned short*)d_ws;
    unsigned short* x2  = x1 + 56623104;
    unsigned short* x3  = x2 + 14155776;
    unsigned short* x4  = x3 + 3538944;
    unsigned short* Wt1 = x4 + 884736;
    unsigned short* Wt2 = Wt1 + 55296;
    unsigned short* Wt3 = Wt2 + 221184;
    unsigned short* zp  = Wt3 + 884736;    // 1KB zero page
    unsigned short* W0f = zp + 512;        // conv0 B table, K=64 layout (4KB)

    wprep_all<<<568, 256, 0, stream>>>(k0, k1, k2, k3, W0f, Wt1, Wt2, Wt3, zp);
    conv0_p2<<<3456, 256, 0, stream>>>(x, W0f, (const float*)zp, b0, g0, be0, m0, v0, x1);
    conv_mfma_lds<32, 64, 48, 24, 2, 4, 1, 1, 1, 1728><<<1728, 256, 0, stream>>>(x1, Wt1, zp, b1, g1, be1, m1, v1, x2);
    conv_mfma_lds<64, 128, 24, 12, 1, 4, 2, 1, 1, 864><<<864, 256, 0, stream>>>(x2, Wt2, zp, b2, g2, be2, m2, v2, x3);
    conv_mfma_lds<128, 256, 12, 6, 1, 1, 4, 4, 2, 864><<<864, 256, 0, stream>>>(x3, Wt3, zp, b3, g3, be3, m3, v3, x4);
    head_kernel<<<16, 256, 0, stream>>>(x4, w1k, w1b, wg, wbe, wm, wv, w2k, w2b, (float*)d_out);
}